// Round 1
// baseline (108109.375 us; speedup 1.0000x reference)
//
#include <hip/hip_runtime.h>
#include <cstdint>
#include <cstddef>

#define BB 128
#define TT 512
#define VV 512
#define EE 512
#define HH 1024
#define NBLK 256
#define BHS ((size_t)BB * HH)

// ---------- threefry2x32, JAX partitionable scheme. VERIFIED — do not touch. ----------
__device__ __forceinline__ float tf_uniform(unsigned i) {
  unsigned x0 = 0u;
  unsigned x1 = i;
  const unsigned k0 = 0u, k1 = 1u, k2 = 0x1BD11BDBu;
  x0 += k0; x1 += k1;
#define ROTL_(v, r) (((v) << (r)) | ((v) >> (32 - (r))))
#define RND_(r) { x0 += x1; x1 = ROTL_(x1, (r)); x1 ^= x0; }
  RND_(13) RND_(15) RND_(26) RND_(6)   x0 += k1; x1 += k2 + 1u;
  RND_(17) RND_(29) RND_(16) RND_(24)  x0 += k2; x1 += k0 + 2u;
  RND_(13) RND_(15) RND_(26) RND_(6)   x0 += k0; x1 += k1 + 3u;
  RND_(17) RND_(29) RND_(16) RND_(24)  x0 += k1; x1 += k2 + 4u;
  RND_(13) RND_(15) RND_(26) RND_(6)   x0 += k2; x1 += k0 + 5u;
#undef RND_
#undef ROTL_
  unsigned bits = x0 ^ x1;
  unsigned fb = (bits >> 9) | 0x3f800000u;
  return __uint_as_float(fb) - 1.0f;
}

// ---------- grid barrier: monotonic counter, agent scope. Co-residency via cooperative launch. ----------
__device__ __forceinline__ void gridbar(unsigned* bar, unsigned target) {
  __syncthreads();
  if (threadIdx.x == 0) {
    __threadfence();  // release: publish this block's writes (L2 wb on gfx950 agent scope)
    __hip_atomic_fetch_add(bar, 1u, __ATOMIC_RELAXED, __HIP_MEMORY_SCOPE_AGENT);
    // spin with RMW(0): guaranteed to read the coherence point (no stale-L2 deadlock)
    while (__hip_atomic_fetch_add(bar, 0u, __ATOMIC_RELAXED, __HIP_MEMORY_SCOPE_AGENT) < target) {
      __builtin_amdgcn_s_sleep(1);
    }
    __threadfence();  // acquire: invalidate so subsequent reads are fresh
  }
  __syncthreads();
}

__global__ __launch_bounds__(256) void init_kernel(float* __restrict__ h0T,
                                                   float* __restrict__ c0T,
                                                   float* __restrict__ h1T,
                                                   float* __restrict__ c1T,
                                                   unsigned* __restrict__ bar) {
  int tid = blockIdx.x * 256 + threadIdx.x;
  if (tid == 0) *bar = 0u;
  if (tid < (int)BHS) {
    h0T[tid] = 0.f; c0T[tid] = 0.f; h1T[tid] = 0.f; c1T[tid] = 0.f;
  }
}

// ============================================================================
// Persistent kernel. 256 blocks x 256 threads, all 512 timesteps on-device.
// State h,c stored TRANSPOSED [H][B] so LDS staging and cell writes vectorize.
// Block bn owns hidden units u in [bn*4, bn*4+4) -> 16 gate columns (i,f,g,o),
// full-K GEMM, cell fused in epilogue. fc: block = (rb=bn>>6: 32 rows, cb=bn&63: 8 cols).
// 3 grid barriers per step: (P1 cell0) -> (P2 cell1) -> (P3 fc/argmax) -> next t.
// ============================================================================
__global__ __launch_bounds__(256, 1) void lstm_persistent(
    const int* __restrict__ seq,
    const float* __restrict__ teacher_p,
    const float* __restrict__ emb,
    const float* __restrict__ Wih0, const float* __restrict__ Whh0,
    const float* __restrict__ bih0, const float* __restrict__ bhh0,
    const float* __restrict__ Wih1, const float* __restrict__ Whh1,
    const float* __restrict__ bih1, const float* __restrict__ bhh1,
    const float* __restrict__ fcw, const float* __restrict__ fcb,
    float* __restrict__ out,
    float* __restrict__ h0T, float* __restrict__ c0T,
    float* __restrict__ h1T, float* __restrict__ c1T,
    unsigned long long* __restrict__ fcpart,
    unsigned* __restrict__ bar) {
  __shared__ float Xs[32][132];   // k x b tile (stride 132: 16B-aligned rows, uniform banks)
  __shared__ float Ws2[16][36];   // c x k tile for gate weights
  __shared__ float Xsf[64][36];   // fc: k x b(32)
  __shared__ float Wsf[8][68];    // fc: c x k
  __shared__ int tok_s[BB];

  const int tid = threadIdx.x;
  const int bn  = blockIdx.x;
  const int ty  = tid >> 3;   // 0..31: rows ty*4..ty*4+3
  const int tx  = tid & 7;    // 0..7 : cols tx*2, tx*2+1 (of 16)

  const float tp = teacher_p[0];

  // persistent per-thread cell-bias registers (role fixed across steps)
  float bc0[2][4], bc1[2][4];
#pragma unroll
  for (int r = 0; r < 2; ++r) {
    int j = (tid + (r << 8)) >> 7;   // 0..3
    int u = (bn << 2) + j;
#pragma unroll
    for (int g = 0; g < 4; ++g) {
      bc0[r][g] = bih0[g * HH + u] + bhh0[g * HH + u];
      bc1[r][g] = bih1[g * HH + u] + bhh1[g * HH + u];
    }
  }

  // W-staging row pointers (used by tid<128): col c=tid>>3 -> gate row g*H + bn*4 + j
  const int wc  = tid >> 3;
  const int wkq = tid & 7;
  const int gr  = (wc >> 2) * HH + (bn << 2) + (wc & 3);
  const float* wih0row = Wih0 + (size_t)gr * EE;
  const float* whh0row = Whh0 + (size_t)gr * HH;
  const float* wih1row = Wih1 + (size_t)gr * HH;
  const float* whh1row = Whh1 + (size_t)gr * HH;

  // fc mapping
  const int rb = bn >> 6, cb = bn & 63;
  const int fb = tid >> 3;                    // 0..31 local row
  const int fcc = tid & 7;                    // 0..7 local col
  const int fn = (cb << 3) + fcc;             // global col
  const float fcbr = fcb[fn];
  const float* fcwrow = fcw + (size_t)((cb << 3) + (tid >> 4)) * HH;  // stage row (tid<128)

  unsigned target = 0;

  for (int t = 0; t < TT; ++t) {
    const float* h0r = h0T + (size_t)(t & 1) * BHS;
    float*       h0w = h0T + (size_t)((t + 1) & 1) * BHS;
    const float* h1r = h1T + (size_t)(t & 1) * BHS;
    float*       h1w = h1T + (size_t)((t + 1) & 1) * BHS;

    // ---------------- token select (redundant per block, deterministic) ----------------
    {
      int b = tid >> 1, h = tid & 1;
      unsigned long long best = 0ull;
      if (t > 0) {
        const unsigned long long* fp = fcpart + ((size_t)b << 6);
#pragma unroll 8
        for (int i = 0; i < 32; ++i) {
          unsigned long long k2 = fp[(i << 1) + h];
          if (k2 > best) best = k2;
        }
        unsigned long long o = __shfl_xor(best, 1);
        if (o > best) best = o;
      }
      if (h == 0) {
        int sel;
        if (t == 0) {
          sel = seq[(size_t)b * TT];
        } else {
          float uu = tf_uniform((unsigned)(t * BB + b));
          sel = (uu < tp) ? seq[(size_t)b * TT + t]
                          : (int)(0xFFFFFFFFu - (unsigned)(best & 0xFFFFFFFFull));
        }
        tok_s[b] = sel;
      }
    }
    __syncthreads();

    // ---------------- P1: layer0 gates (K=1536: emb 16 tiles + h0r 32 tiles) + cell0 ----------------
    {
      float acc[4][2] = {{0.f,0.f},{0.f,0.f},{0.f,0.f},{0.f,0.f}};
      float4 x0, x1, x2, x3, w;

      auto pf = [&](int kt) {
        if (kt < 16) {
          const int kb = kt << 5;
          { int f=tid;     int b=f>>3, kq=f&7; int tk=tok_s[b];
            x0 = tk ? *(const float4*)(emb + ((size_t)tk<<9) + kb + (kq<<2)) : make_float4(0.f,0.f,0.f,0.f); }
          { int f=tid+256; int b=f>>3, kq=f&7; int tk=tok_s[b];
            x1 = tk ? *(const float4*)(emb + ((size_t)tk<<9) + kb + (kq<<2)) : make_float4(0.f,0.f,0.f,0.f); }
          { int f=tid+512; int b=f>>3, kq=f&7; int tk=tok_s[b];
            x2 = tk ? *(const float4*)(emb + ((size_t)tk<<9) + kb + (kq<<2)) : make_float4(0.f,0.f,0.f,0.f); }
          { int f=tid+768; int b=f>>3, kq=f&7; int tk=tok_s[b];
            x3 = tk ? *(const float4*)(emb + ((size_t)tk<<9) + kb + (kq<<2)) : make_float4(0.f,0.f,0.f,0.f); }
          if (tid < 128) w = *(const float4*)(wih0row + kb + (wkq<<2));
        } else {
          const float* src = h0r + ((size_t)(kt - 16) << 5) * BB;
          { int f=tid;     x0 = *(const float4*)(src + (f>>5)*BB + ((f&31)<<2)); }
          { int f=tid+256; x1 = *(const float4*)(src + (f>>5)*BB + ((f&31)<<2)); }
          { int f=tid+512; x2 = *(const float4*)(src + (f>>5)*BB + ((f&31)<<2)); }
          { int f=tid+768; x3 = *(const float4*)(src + (f>>5)*BB + ((f&31)<<2)); }
          if (tid < 128) w = *(const float4*)(whh0row + ((kt - 16) << 5) + (wkq<<2));
        }
      };
      auto st = [&](int kt) {
        if (kt < 16) {  // transpose scalar stores (gather path)
          { int f=tid;     int b=f>>3, kk=(f&7)<<2; Xs[kk][b]=x0.x; Xs[kk+1][b]=x0.y; Xs[kk+2][b]=x0.z; Xs[kk+3][b]=x0.w; }
          { int f=tid+256; int b=f>>3, kk=(f&7)<<2; Xs[kk][b]=x1.x; Xs[kk+1][b]=x1.y; Xs[kk+2][b]=x1.z; Xs[kk+3][b]=x1.w; }
          { int f=tid+512; int b=f>>3, kk=(f&7)<<2; Xs[kk][b]=x2.x; Xs[kk+1][b]=x2.y; Xs[kk+2][b]=x2.z; Xs[kk+3][b]=x2.w; }
          { int f=tid+768; int b=f>>3, kk=(f&7)<<2; Xs[kk][b]=x3.x; Xs[kk+1][b]=x3.y; Xs[kk+2][b]=x3.z; Xs[kk+3][b]=x3.w; }
        } else {        // vector stores (transposed-state path)
          { int f=tid;     *(float4*)&Xs[f>>5][(f&31)<<2] = x0; }
          { int f=tid+256; *(float4*)&Xs[f>>5][(f&31)<<2] = x1; }
          { int f=tid+512; *(float4*)&Xs[f>>5][(f&31)<<2] = x2; }
          { int f=tid+768; *(float4*)&Xs[f>>5][(f&31)<<2] = x3; }
        }
        if (tid < 128) *(float4*)&Ws2[wc][wkq<<2] = w;
      };

      pf(0);
      for (int kt = 0; kt < 48; ++kt) {
        st(kt);
        __syncthreads();
        if (kt < 47) pf(kt + 1);   // latency hides under compute below
#pragma unroll
        for (int k4 = 0; k4 < 8; ++k4) {
          float w0[4], w1[4];
          *(float4*)w0 = *(const float4*)&Ws2[tx << 1][k4 << 2];
          *(float4*)w1 = *(const float4*)&Ws2[(tx << 1) + 1][k4 << 2];
#pragma unroll
          for (int kk = 0; kk < 4; ++kk) {
            float a[4];
            *(float4*)a = *(const float4*)&Xs[(k4 << 2) + kk][ty << 2];
#pragma unroll
            for (int i = 0; i < 4; ++i) {
              acc[i][0] = fmaf(a[i], w0[kk], acc[i][0]);
              acc[i][1] = fmaf(a[i], w1[kk], acc[i][1]);
            }
          }
        }
        __syncthreads();
      }

      // fused cell0 epilogue
      float* gbuf = &Xs[0][0];   // reuse as [128][17]
#pragma unroll
      for (int i = 0; i < 4; ++i) {
        int r = (ty << 2) + i;
        gbuf[r * 17 + (tx << 1)]     = acc[i][0];
        gbuf[r * 17 + (tx << 1) + 1] = acc[i][1];
      }
      __syncthreads();
#pragma unroll
      for (int r = 0; r < 2; ++r) {
        int idx = tid + (r << 8);
        int b = idx & 127, j = idx >> 7;
        float gi = gbuf[b * 17 + j]      + bc0[r][0];
        float gf = gbuf[b * 17 + 4 + j]  + bc0[r][1];
        float gg = gbuf[b * 17 + 8 + j]  + bc0[r][2];
        float go = gbuf[b * 17 + 12 + j] + bc0[r][3];
        float i_ = 1.f / (1.f + expf(-gi));
        float f_ = 1.f / (1.f + expf(-gf));
        float g_ = tanhf(gg);
        float o_ = 1.f / (1.f + expf(-go));
        size_t off = ((size_t)((bn << 2) + j)) * BB + b;
        float cn = f_ * c0T[off] + i_ * g_;
        c0T[off] = cn;
        h0w[off] = o_ * tanhf(cn);
      }
    }
    target += NBLK; gridbar(bar, target);

    // ---------------- P2: layer1 gates (K=2048: h0w 32 + h1r 32 tiles) + cell1 ----------------
    {
      float acc[4][2] = {{0.f,0.f},{0.f,0.f},{0.f,0.f},{0.f,0.f}};
      float4 x0, x1, x2, x3, w;

      auto pf2 = [&](int kt) {
        const float* src = (kt < 32) ? (h0w + ((size_t)kt << 5) * BB)
                                     : (h1r + ((size_t)(kt - 32) << 5) * BB);
        { int f=tid;     x0 = *(const float4*)(src + (f>>5)*BB + ((f&31)<<2)); }
        { int f=tid+256; x1 = *(const float4*)(src + (f>>5)*BB + ((f&31)<<2)); }
        { int f=tid+512; x2 = *(const float4*)(src + (f>>5)*BB + ((f&31)<<2)); }
        { int f=tid+768; x3 = *(const float4*)(src + (f>>5)*BB + ((f&31)<<2)); }
        if (tid < 128) {
          w = (kt < 32) ? *(const float4*)(wih1row + (kt << 5) + (wkq<<2))
                        : *(const float4*)(whh1row + ((kt - 32) << 5) + (wkq<<2));
        }
      };
      auto st2 = [&]() {
        { int f=tid;     *(float4*)&Xs[f>>5][(f&31)<<2] = x0; }
        { int f=tid+256; *(float4*)&Xs[f>>5][(f&31)<<2] = x1; }
        { int f=tid+512; *(float4*)&Xs[f>>5][(f&31)<<2] = x2; }
        { int f=tid+768; *(float4*)&Xs[f>>5][(f&31)<<2] = x3; }
        if (tid < 128) *(float4*)&Ws2[wc][wkq<<2] = w;
      };

      pf2(0);
      for (int kt = 0; kt < 64; ++kt) {
        st2();
        __syncthreads();
        if (kt < 63) pf2(kt + 1);
#pragma unroll
        for (int k4 = 0; k4 < 8; ++k4) {
          float w0[4], w1[4];
          *(float4*)w0 = *(const float4*)&Ws2[tx << 1][k4 << 2];
          *(float4*)w1 = *(const float4*)&Ws2[(tx << 1) + 1][k4 << 2];
#pragma unroll
          for (int kk = 0; kk < 4; ++kk) {
            float a[4];
            *(float4*)a = *(const float4*)&Xs[(k4 << 2) + kk][ty << 2];
#pragma unroll
            for (int i = 0; i < 4; ++i) {
              acc[i][0] = fmaf(a[i], w0[kk], acc[i][0]);
              acc[i][1] = fmaf(a[i], w1[kk], acc[i][1]);
            }
          }
        }
        __syncthreads();
      }

      float* gbuf = &Xs[0][0];
#pragma unroll
      for (int i = 0; i < 4; ++i) {
        int r = (ty << 2) + i;
        gbuf[r * 17 + (tx << 1)]     = acc[i][0];
        gbuf[r * 17 + (tx << 1) + 1] = acc[i][1];
      }
      __syncthreads();
#pragma unroll
      for (int r = 0; r < 2; ++r) {
        int idx = tid + (r << 8);
        int b = idx & 127, j = idx >> 7;
        float gi = gbuf[b * 17 + j]      + bc1[r][0];
        float gf = gbuf[b * 17 + 4 + j]  + bc1[r][1];
        float gg = gbuf[b * 17 + 8 + j]  + bc1[r][2];
        float go = gbuf[b * 17 + 12 + j] + bc1[r][3];
        float i_ = 1.f / (1.f + expf(-gi));
        float f_ = 1.f / (1.f + expf(-gf));
        float g_ = tanhf(gg);
        float o_ = 1.f / (1.f + expf(-go));
        size_t off = ((size_t)((bn << 2) + j)) * BB + b;
        float cn = f_ * c1T[off] + i_ * g_;
        c1T[off] = cn;
        h1w[off] = o_ * tanhf(cn);
      }
    }
    target += NBLK; gridbar(bar, target);

    // ---------------- P3: fc logits + argmax partial keys ----------------
    {
      float facc = 0.f;
      float4 y0, y1, fw;
      auto pf3 = [&](int kt) {
        const float* src = h1w + ((size_t)kt << 6) * BB + ((size_t)rb << 5);
        { int f=tid;     y0 = *(const float4*)(src + (f>>3)*BB + ((f&7)<<2)); }
        { int f=tid+256; y1 = *(const float4*)(src + (f>>3)*BB + ((f&7)<<2)); }
        if (tid < 128) fw = *(const float4*)(fcwrow + (kt << 6) + ((tid & 15) << 2));
      };
      auto st3 = [&]() {
        { int f=tid;     *(float4*)&Xsf[f>>3][(f&7)<<2] = y0; }
        { int f=tid+256; *(float4*)&Xsf[f>>3][(f&7)<<2] = y1; }
        if (tid < 128) *(float4*)&Wsf[tid >> 4][(tid & 15) << 2] = fw;
      };
      pf3(0);
      for (int kt = 0; kt < 16; ++kt) {
        st3();
        __syncthreads();
        if (kt < 15) pf3(kt + 1);
#pragma unroll
        for (int k = 0; k < 64; ++k)
          facc = fmaf(Xsf[k][fb], Wsf[fcc][k], facc);
        __syncthreads();
      }
      int b = (rb << 5) + fb;
      float lg = facc + fcbr;
      out[((size_t)b * TT + t) * VV + fn] = lg;
      unsigned sbits = __float_as_uint(lg);
      sbits = (sbits & 0x80000000u) ? ~sbits : (sbits | 0x80000000u);
      unsigned long long key = ((unsigned long long)sbits << 32) |
                               (unsigned long long)(0xFFFFFFFFu - (unsigned)fn);
#pragma unroll
      for (int off = 4; off > 0; off >>= 1) {
        unsigned long long o = __shfl_down(key, off, 8);
        if (o > key) key = o;
      }
      if (fcc == 0) fcpart[((size_t)b << 6) + cb] = key;
    }
    target += NBLK; gridbar(bar, target);
  }
}

extern "C" void kernel_launch(void* const* d_in, const int* in_sizes, int n_in,
                              void* d_out, int out_size, void* d_ws, size_t ws_size,
                              hipStream_t stream) {
  const int*   seq       = (const int*)d_in[0];
  const float* teacher_p = (const float*)d_in[2];
  const float* embeds    = (const float*)d_in[3];
  const float* W_ih0     = (const float*)d_in[4];
  const float* W_hh0     = (const float*)d_in[5];
  const float* b_ih0     = (const float*)d_in[6];
  const float* b_hh0     = (const float*)d_in[7];
  const float* W_ih1     = (const float*)d_in[8];
  const float* W_hh1     = (const float*)d_in[9];
  const float* b_ih1     = (const float*)d_in[10];
  const float* b_hh1     = (const float*)d_in[11];
  const float* fc_w      = (const float*)d_in[12];
  const float* fc_b      = (const float*)d_in[13];
  float* out = (float*)d_out;

  // workspace: h0T(2) | c0T | h1T(2) | c1T  (transposed [H][B]) | fcpart | bar
  char* ws = (char*)d_ws;
  float* h0T = (float*)(ws);
  float* c0T = (float*)(ws + 2 * BHS * 4);
  float* h1T = (float*)(ws + 3 * BHS * 4);
  float* c1T = (float*)(ws + 5 * BHS * 4);
  unsigned long long* fcpart = (unsigned long long*)(ws + 6 * BHS * 4);   // 128*64 u64 = 64 KB
  unsigned* bar = (unsigned*)(ws + 6 * BHS * 4 + 65536);

  init_kernel<<<512, 256, 0, stream>>>(h0T, c0T, h1T, c1T, bar);

  void* args[] = {
    (void*)&seq, (void*)&teacher_p, (void*)&embeds,
    (void*)&W_ih0, (void*)&W_hh0, (void*)&b_ih0, (void*)&b_hh0,
    (void*)&W_ih1, (void*)&W_hh1, (void*)&b_ih1, (void*)&b_hh1,
    (void*)&fc_w, (void*)&fc_b, (void*)&out,
    (void*)&h0T, (void*)&c0T, (void*)&h1T, (void*)&c1T,
    (void*)&fcpart, (void*)&bar
  };
  hipError_t err = hipLaunchCooperativeKernel((void*)lstm_persistent,
                                              dim3(NBLK), dim3(256), args, 0, stream);
  if (err != hipSuccess) {
    // fallback: plain launch. 256 blocks of 256 thr (30KB LDS, LB(256,1)) are
    // trivially co-resident on 256 CUs; barrier remains sound.
    lstm_persistent<<<dim3(NBLK), dim3(256), 0, stream>>>(
        seq, teacher_p, embeds, W_ih0, W_hh0, b_ih0, b_hh0,
        W_ih1, W_hh1, b_ih1, b_hh1, fc_w, fc_b, out,
        h0T, c0T, h1T, c1T, fcpart, bar);
  }
}